// Round 4
// baseline (646.150 us; speedup 1.0000x reference)
//
#include <hip/hip_runtime.h>

#define NBINS 20
#define C 128
#define BLOCKS 2048

// clang-native vector type: required by __builtin_nontemporal_load.
typedef float vf4 __attribute__((ext_vector_type(4)));

// ws layout: float bcsum[BLOCKS][NBINS] | unsigned bcc[BLOCKS][NBINS] (320 KB).
// Every block writes all of its 20 slots unconditionally -> no ws zeroing
// needed (the 0xAA poison is never read). NOTE: the harness's 2 GB ws
// re-poison fill (~318 us at write roofline) is a fixed floor we don't control.

// pass1: contiguous block partitioning (block b owns ~489 consecutive rows;
// its 4 waves interleave at 8-row steps -> the block streams a sliding 16 KB
// contiguous window for DRAM page locality). 8 lanes/row, 4 vf4 loads/lane,
// register double-buffered so the next half-step's 5 loads stay in flight
// across the current scan/shfl/atomic tail. NO global atomics: per-block
// partials are written to private slots at block end.
__global__ __launch_bounds__(256) void ece_pass1(
    const float* __restrict__ sm, const int* __restrict__ labels, int N,
    float* __restrict__ bcsum, unsigned* __restrict__ bcc) {
  __shared__ float s_csum[NBINS];
  __shared__ unsigned s_cc[NBINS];  // cnt in [15:0] | cor in [31:16]
  const int tid = threadIdx.x;
  if (tid < NBINS) { s_csum[tid] = 0.f; s_cc[tid] = 0u; }
  __syncthreads();

  const int lane = tid & 63;
  const int p = lane & 7;   // position within row (8 lanes/row)
  const int r = lane >> 3;  // row within the 8-row half-step
  const int w = tid >> 6;   // wave id in block

  const long long rpb = ((long long)N + BLOCKS - 1) / BLOCKS;  // rows/block
  const long long lo  = (long long)blockIdx.x * rpb;
  const long long hi  = min(lo + rpb, (long long)N);

  vf4 va[4], vb[4];
  int la = 0, lb = 0;

  // Issue the 4 tile loads + label load for the 8-row half-step at row base rb.
  auto issue = [&](long long rb, vf4 (&v)[4], int& lab) {
    const long long row = rb + r;
    if (row < hi) {
      const vf4* rp = (const vf4*)(sm + row * (long long)C);
#pragma unroll
      for (int k = 0; k < 4; ++k)
        v[k] = __builtin_nontemporal_load(rp + p + k * 8);  // one-shot stream
      lab = labels[row];  // 8 distinct dwords/wave, contiguous 32 B
    } else {
#pragma unroll
      for (int k = 0; k < 4; ++k) v[k] = (vf4){-2.f, -2.f, -2.f, -2.f};
      lab = -1;
    }
  };

  // In-lane argmax over 16 values (ascending flat index, strict '>' keeps the
  // first occurrence = jnp.argmax tie-break), then 8-lane xor reduce, then
  // leader lane does 2 LDS atomics (csum float + packed cnt|cor).
  auto process = [&](long long rb, const vf4 (&v)[4], int lab) {
    float bv = -3.f;
    int bi = 0;
#pragma unroll
    for (int k = 0; k < 4; ++k) {
      const vf4 q = v[k];
      const int b0 = k * 32 + p * 4;
      if (q.x > bv) { bv = q.x; bi = b0; }
      if (q.y > bv) { bv = q.y; bi = b0 + 1; }
      if (q.z > bv) { bv = q.z; bi = b0 + 2; }
      if (q.w > bv) { bv = q.w; bi = b0 + 3; }
    }
#pragma unroll
    for (int off = 1; off <= 4; off <<= 1) {
      const float ov = __shfl_xor(bv, off);
      const int   oi = __shfl_xor(bi, off);
      if (ov > bv || (ov == bv && oi < bi)) { bv = ov; bi = oi; }
    }
    const long long row = rb + r;
    if (p == 0 && row < hi) {
      int bin = (int)ceilf(bv * 20.0f) - 1;  // matches jnp.ceil(conf*20)-1
      bin = min(max(bin, 0), NBINS - 1);
      atomicAdd(&s_csum[bin], bv);
      // per-block rows <= 512 << 2^16 -> packed add is safe
      atomicAdd(&s_cc[bin], 1u + ((bi == lab) ? 0x10000u : 0u));
    }
  };

  // Waves interleave at 8-row granularity within the block's contiguous span:
  // wave w handles bases lo + w*8, +32, +64, ...  (block window = 32 rows).
  long long rb = lo + (long long)w * 8;
  if (rb < hi) {
    issue(rb, va, la);
    while (true) {
      long long rn = rb + 32;
      if (rn < hi) issue(rn, vb, lb);  // prefetch across process() tail
      process(rb, va, la);
      rb = rn;
      if (rb >= hi) break;
      rn = rb + 32;
      if (rn < hi) issue(rn, va, la);
      process(rb, vb, lb);
      rb = rn;
      if (rb >= hi) break;
    }
  }

  __syncthreads();
  if (tid < NBINS) {  // non-atomic private-slot writeout (zeros included)
    bcsum[blockIdx.x * NBINS + tid] = s_csum[tid];
    bcc[blockIdx.x * NBINS + tid]   = s_cc[tid];
  }
}

// pass2: reduce 2048 per-block partials (320 KB, L2-resident).
// 640 threads: thread t -> bin t%20, chunk t/20 (32 chunks of 64 blocks).
__global__ void ece_pass2(const float* __restrict__ bcsum,
                          const unsigned* __restrict__ bcc,
                          float* __restrict__ out, int N) {
  __shared__ double  sc[32][NBINS];
  __shared__ unsigned scnt[32][NBINS];
  __shared__ unsigned scor[32][NBINS];
  const int t = threadIdx.x;
  const int bin = t % NBINS;
  const int chunk = t / NBINS;  // 0..31
  double cs = 0.0;
  unsigned cn = 0, co = 0;
  for (int b = chunk; b < BLOCKS; b += 32) {
    cs += (double)bcsum[b * NBINS + bin];
    const unsigned cc = bcc[b * NBINS + bin];
    cn += cc & 0xFFFFu;
    co += cc >> 16;
  }
  sc[chunk][bin] = cs;
  scnt[chunk][bin] = cn;
  scor[chunk][bin] = co;
  __syncthreads();

  double contrib = 0.0;
  if (t < NBINS) {
    double csum = 0.0;
    unsigned cnt = 0, cor = 0;
#pragma unroll
    for (int g = 0; g < 32; ++g) {
      csum += sc[g][t];
      cnt += scnt[g][t];
      cor += scor[g][t];
    }
    const double safe = cnt ? (double)cnt : 1.0;
    const double avg_conf = csum / safe;
    const double avg_acc  = (double)cor / safe;
    out[1 + t] = cnt ? (float)avg_acc : 0.f;  // ys
    if (cnt) contrib = fabs(avg_conf - avg_acc) * ((double)cnt / (double)N);
  }
#pragma unroll
  for (int off = 16; off >= 1; off >>= 1) contrib += __shfl_down(contrib, off);
  if (t == 0) out[0] = (float)contrib;  // ece
}

extern "C" void kernel_launch(void* const* d_in, const int* in_sizes, int n_in,
                              void* d_out, int out_size, void* d_ws, size_t ws_size,
                              hipStream_t stream) {
  const float* sm     = (const float*)d_in[0];
  const int*   labels = (const int*)d_in[1];
  const int N = in_sizes[1];  // labels count = number of rows

  float*    bcsum = (float*)d_ws;
  unsigned* bcc   = (unsigned*)((char*)d_ws + BLOCKS * NBINS * sizeof(float));

  // No ws memset needed: every bcsum/bcc slot is written unconditionally.
  ece_pass1<<<BLOCKS, 256, 0, stream>>>(sm, labels, N, bcsum, bcc);
  ece_pass2<<<1, 640, 0, stream>>>(bcsum, bcc, (float*)d_out, N);
}